// Round 3
// baseline (1156.570 us; speedup 1.0000x reference)
//
#include <hip/hip_runtime.h>
#include <hip/hip_bf16.h>

// LSTM  B=2048 T=512 F=64 H=128, gates i,f,g,o ; z = [x|h] @ [Wx;Wh] + b
// 256 blocks x 512 thr (8 waves); block owns BB=8 batch rows for all T.
// Weights in registers as bf16 MFMA B-frags; h double-buffered in swizzled
// LDS (bf16); c in registers; gate math redistributed across all 64 lanes.

#define B_ 2048
#define T_ 512
#define F_ 64
#define H_ 128
#define NG_ 512   // 4H
#define BB_ 8     // batch rows per block

typedef __attribute__((ext_vector_type(8))) short short8;
typedef __attribute__((ext_vector_type(4))) float f32x4;

static __device__ __forceinline__ unsigned short f2bf(float f) {
  unsigned u = __float_as_uint(f);
  u += 0x7FFFu + ((u >> 16) & 1u);   // RNE
  return (unsigned short)(u >> 16);
}

static __device__ __forceinline__ float rcp_fast(float x) {
#if __has_builtin(__builtin_amdgcn_rcpf)
  return __builtin_amdgcn_rcpf(x);
#else
  return 1.0f / x;
#endif
}
static __device__ __forceinline__ float ex2(float x) {
#if __has_builtin(__builtin_amdgcn_exp2f)
  return __builtin_amdgcn_exp2f(x);
#else
  return exp2f(x);
#endif
}
#define LOG2E_ 1.4426950408889634f
static __device__ __forceinline__ float sigm(float x) {       // 2 trans ops
  return rcp_fast(1.0f + ex2(-LOG2E_ * x));
}
static __device__ __forceinline__ float tanh_f(float x) {     // 2 trans ops
  return 2.0f * rcp_fast(1.0f + ex2(-2.0f * LOG2E_ * x)) - 1.0f;
}

static __device__ __forceinline__ unsigned pk2(float a, float b) {
  // v_cvt_pk_bf16_f32 via intrinsic; memcpy type-pun (bit_cast rejects
  // __hip_bfloat162: non-trivially-copyable on this ROCm)
  __hip_bfloat162 v = __float22bfloat162_rn(make_float2(a, b));
  unsigned u;
  __builtin_memcpy(&u, &v, sizeof(u));
  return u;
}

__global__ __launch_bounds__(512, 2) void lstm_kernel(
    const float* __restrict__ xin,   // [B,T,F]
    const float* __restrict__ Wx,    // [F,4H]
    const float* __restrict__ Wh,    // [H,4H]
    const float* __restrict__ bvec,  // [4H]
    float* __restrict__ out) {       // [B,T,H]
  // h state, bf16, double-buffered [2][16][H]; XOR-swizzle (halfword ^ (row&7)<<3)
  // makes the A-frag ds_read_b128 conflict-free.
  __shared__ __align__(16) unsigned short hbuf[2][16 * H_];

  const int tid  = threadIdx.x;
  const int lane = tid & 63;
  const int w    = tid >> 6;      // wave 0..7 : n-tile w of each gate
  const int col  = lane & 15;
  const int kgrp = lane >> 4;     // 0..3
  const int b0   = blockIdx.x * BB_;

  // ---- weight B-frags (bf16) in registers: wf[gate][kstep] ----
  // B-frag: lane holds B[k = 8*kgrp + j][n = 128*g + 16*w + col]
  short8 wf[4][6];
  f32x4  biasv[4];
  #pragma unroll
  for (int g = 0; g < 4; ++g) {
    int n = 128 * g + 16 * w + col;
    float bs = bvec[n];
    biasv[g] = (f32x4){bs, bs, bs, bs};
    #pragma unroll
    for (int ks = 0; ks < 6; ++ks) {
      const float* src = (ks < 2)
          ? (Wx + (size_t)(32 * ks + 8 * kgrp) * NG_ + n)
          : (Wh + (size_t)(32 * (ks - 2) + 8 * kgrp) * NG_ + n);
      short8 fr;
      #pragma unroll
      for (int j = 0; j < 8; ++j) fr[j] = (short)f2bf(src[(size_t)j * NG_]);
      wf[g][ks] = fr;
    }
  }

  // zero both h buffers (h(-1) = 0; garbage rows stay 0 forever)
  {
    unsigned* p = (unsigned*)&hbuf[0][0];
    #pragma unroll
    for (int i = 0; i < 4; ++i) p[tid + 512 * i] = 0u;
  }

  // loop-invariant LDS addresses (halfword units)
  const int swz = (col & 7) << 3;
  const int ra0 = (col * H_ +  8 * kgrp) ^ swz;        // kstep 0 (kstep2 = +64)
  const int ra1 = (col * H_ + 32 + 8 * kgrp) ^ swz;    // kstep 1 (kstep3 = +64)
  // redistributed row ownership: every lane owns 2 real rows
  const int R0 = (kgrp < 2) ? 4 * kgrp : 4 * (kgrp - 2) + 2;
  const int R1 = R0 + 1;
  const int ci = 16 * w + col;
  const int wa0 = (R0 * H_ + ci) ^ ((R0 & 7) << 3);
  const int wa1 = (R1 * H_ + ci) ^ ((R1 & 7) << 3);

  // x A-frag pointers: lane reads x[b0+row][t][8*kgrp + j (+32)]
  const int brow = (col < BB_) ? col : (BB_ - 1);      // clamp garbage rows
  const float* xb = xin + (size_t)(b0 + brow) * T_ * F_ + 8 * kgrp;

  // prefetch x(0) and x(1)  (depth-2)
  float4 pA0 = *(const float4*)(xb + 0);
  float4 pA1 = *(const float4*)(xb + 4);
  float4 pA2 = *(const float4*)(xb + 32);
  float4 pA3 = *(const float4*)(xb + 36);
  float4 pB0 = *(const float4*)(xb + F_ + 0);
  float4 pB1 = *(const float4*)(xb + F_ + 4);
  float4 pB2 = *(const float4*)(xb + F_ + 32);
  float4 pB3 = *(const float4*)(xb + F_ + 36);

  int o0 = ((b0 + R0) * T_) * H_ + ci;   // out offsets (elements), += H_ per t
  int o1 = ((b0 + R1) * T_) * H_ + ci;
  float c0 = 0.f, c1 = 0.f;

  __syncthreads();

  auto step = [&](float4& P0, float4& P1, float4& P2, float4& P3,
                  int rs, int ws, int tload) {
    // x(t) -> bf16 A-frags
    union { short8 s8; unsigned u[4]; } ua, ub;
    ua.u[0] = pk2(P0.x, P0.y); ua.u[1] = pk2(P0.z, P0.w);
    ua.u[2] = pk2(P1.x, P1.y); ua.u[3] = pk2(P1.z, P1.w);
    ub.u[0] = pk2(P2.x, P2.y); ub.u[1] = pk2(P2.z, P2.w);
    ub.u[2] = pk2(P3.x, P3.y); ub.u[3] = pk2(P3.z, P3.w);
    short8 xa0 = ua.s8, xa1 = ub.s8;

    // issue prefetch of x(tload) early (hides HBM latency under MFMA+gates)
    {
      const float* xp = xb + (size_t)tload * F_;
      P0 = *(const float4*)(xp + 0);
      P1 = *(const float4*)(xp + 4);
      P2 = *(const float4*)(xp + 32);
      P3 = *(const float4*)(xp + 36);
    }

    // h(t-1) A-frags from LDS
    const unsigned short* hr = &hbuf[rs][0];
    short8 ha0 = *(const short8*)(hr + ra0);
    short8 ha1 = *(const short8*)(hr + ra1);
    short8 ha2 = *(const short8*)(hr + ra0 + 64);
    short8 ha3 = *(const short8*)(hr + ra1 + 64);

    // z[g] = bias + x@Wx + h@Wh  (fp32 accum)
    f32x4 acc[4];
    #pragma unroll
    for (int g = 0; g < 4; ++g) {
      f32x4 a = biasv[g];
      a = __builtin_amdgcn_mfma_f32_16x16x32_bf16(xa0, wf[g][0], a, 0, 0, 0);
      a = __builtin_amdgcn_mfma_f32_16x16x32_bf16(xa1, wf[g][1], a, 0, 0, 0);
      a = __builtin_amdgcn_mfma_f32_16x16x32_bf16(ha0, wf[g][2], a, 0, 0, 0);
      a = __builtin_amdgcn_mfma_f32_16x16x32_bf16(ha1, wf[g][3], a, 0, 0, 0);
      a = __builtin_amdgcn_mfma_f32_16x16x32_bf16(ha2, wf[g][4], a, 0, 0, 0);
      a = __builtin_amdgcn_mfma_f32_16x16x32_bf16(ha3, wf[g][5], a, 0, 0, 0);
      acc[g] = a;
    }

    // redistribute rows 2,3 of each lane's quad to lanes 32..63 so ALL 64
    // lanes do gate math on 2 real rows (halves the transcendental cost)
    const bool up = (lane & 32) != 0;
    float z0[4], z1[4];
    #pragma unroll
    for (int g = 0; g < 4; ++g) {
      float p2 = __shfl_xor(acc[g][2], 32);
      float p3 = __shfl_xor(acc[g][3], 32);
      z0[g] = up ? p2 : acc[g][0];
      z1[g] = up ? p3 : acc[g][1];
    }

    // gates + state update (rows R0, R1)
    float i0 = sigm(z0[0]), f0 = sigm(z0[1]), g0 = tanh_f(z0[2]), q0 = sigm(z0[3]);
    float i1 = sigm(z1[0]), f1 = sigm(z1[1]), g1 = tanh_f(z1[2]), q1 = sigm(z1[3]);
    c0 = f0 * c0 + i0 * g0;
    c1 = f1 * c1 + i1 * g1;
    float h0 = q0 * tanh_f(c0);
    float h1 = q1 * tanh_f(c1);

    // h(t) feedback (bf16, swizzled) + fp32 output (nontemporal stream)
    unsigned hp = pk2(h0, h1);
    unsigned short* hw = &hbuf[ws][0];
    hw[wa0] = (unsigned short)hp;
    hw[wa1] = (unsigned short)(hp >> 16);
    __builtin_nontemporal_store(h0, out + o0);
    __builtin_nontemporal_store(h1, out + o1);
    o0 += H_;
    o1 += H_;

    __syncthreads();   // h(t) visible; next step reads buffer ws
  };

  #pragma unroll 1
  for (int it = 0; it < T_ / 2; ++it) {
    int t0 = 2 * it;
    int lA = t0 + 2; if (lA > T_ - 1) lA = T_ - 1;
    int lB = t0 + 3; if (lB > T_ - 1) lB = T_ - 1;
    step(pA0, pA1, pA2, pA3, 0, 1, lA);   // even t: read buf0, write buf1
    step(pB0, pB1, pB2, pB3, 1, 0, lB);   // odd  t: read buf1, write buf0
  }
}

extern "C" void kernel_launch(void* const* d_in, const int* in_sizes, int n_in,
                              void* d_out, int out_size, void* d_ws, size_t ws_size,
                              hipStream_t stream) {
  const float* xin = (const float*)d_in[0];
  const float* Wx  = (const float*)d_in[1];
  const float* Wh  = (const float*)d_in[2];
  const float* b   = (const float*)d_in[3];
  float* out = (float*)d_out;
  lstm_kernel<<<B_ / BB_, 512, 0, stream>>>(xin, Wx, Wh, b, out);
}